// Round 1
// baseline (285.741 us; speedup 1.0000x reference)
//
#include <hip/hip_runtime.h>
#include <hip/hip_bf16.h>
#include <cstdint>
#include <cstddef>

#define N_O 50000
#define N_Q 50000
#define NE  1600000
// LATENT=128, HEADS=4, HEAD_DIM=32

#define EDGE_BLOCKS  (NE / 64)             // 25000 (2 waves x 32 edges, 128 thr)
#define VP_TILES     ((N_O + 31) / 32)     // 1563 (one 32-row tile per WAVE)
#define VP_BLOCKS    ((VP_TILES + 1) / 2)  // 782  (2 waves/block)
#define RP_BLOCKS    ((N_Q + 128) / 128)   // 391
#define WCAP 264                           // attn LDS plane stride (floats)

typedef __attribute__((ext_vector_type(8)))  short short8;
typedef __attribute__((ext_vector_type(16))) float f32x16;

__device__ inline unsigned short f2bf(float x) {
    __hip_bfloat16 hb = __float2bfloat16(x);
    return *reinterpret_cast<unsigned short*>(&hb);
}

__device__ inline unsigned pk2(float a, float b) {
    __hip_bfloat162 t = __float22bfloat162_rn(make_float2(a, b));
    return *reinterpret_cast<unsigned*>(&t);
}

// ---------------------------------------------------------------------------
// pack (R6/R10-proven, unchanged): bf16 weight tensors for the MFMA edge MLP.
//  W1cT [128 hidden][8 attr] bf16 : attrs = [Wq+Wr (3), Wo-Wr (3), b1, 0]
//  W2tb [4 head][128 hidden] bf16
//  scal fp32: [0]=1/(2 sigma^2), [1..4]=b2
// ---------------------------------------------------------------------------
__global__ void pack_kernel(const float* __restrict__ W1, const float* __restrict__ b1,
                            const float* __restrict__ W2, const float* __restrict__ b2,
                            const float* __restrict__ log_sigma,
                            unsigned short* __restrict__ W1cT,
                            unsigned short* __restrict__ W2tb,
                            float* __restrict__ scal) {
    int j = threadIdx.x;
    if (j < 128) {
        #pragma unroll
        for (int a = 0; a < 3; ++a) {
            W1cT[j * 8 + a]     = f2bf(W1[(3 + a) * 128 + j] + W1[a * 128 + j]); // pq coef
            W1cT[j * 8 + 3 + a] = f2bf(W1[(6 + a) * 128 + j] - W1[a * 128 + j]); // po coef
        }
        W1cT[j * 8 + 6] = f2bf(b1[j]);
        W1cT[j * 8 + 7] = 0;
        #pragma unroll
        for (int hd = 0; hd < 4; ++hd)
            W2tb[hd * 128 + j] = f2bf(W2[j * 4 + hd]);
    } else if (j == 128) {
        float sigma = expf(log_sigma[0]) + 1e-6f;
        scal[0] = 1.0f / (2.0f * sigma * sigma);
        scal[1] = b2[0]; scal[2] = b2[1]; scal[3] = b2[2]; scal[4] = b2[3];
    }
}

// ---------------------------------------------------------------------------
// rowptr body (proven logic, unchanged): rp[q] = lower_bound(dst,q)
// ---------------------------------------------------------------------------
__device__ void rowptr_body(int bid, const int* __restrict__ dst, int* __restrict__ rp) {
    int q = bid * 128 + threadIdx.x;
    if (q > N_Q) return;
    int lo = 0, hi = NE;
    while (lo < hi) {
        int mid = (lo + hi) >> 1;
        if (dst[mid] < q) lo = mid + 1; else hi = mid;
    }
    rp[q] = lo;
}

// ---------------------------------------------------------------------------
// vproj (NEW, MFMA): v = h_obs @ Wv + bv, one 32-row tile per wave, no LDS.
// D[vcol][node]: A = Wv^T block (A[r][k] = Wv[k][32c+r], per-lane strided
// loads, L1/L2-hot), B = h rows (per-lane contiguous 32B loads).
// 3-pass bf16 split keeps the result at fp32-level accuracy:
//   acc += w_hi*h_hi + w_hi*h_lo + w_lo*h_hi   (lo*lo ~ 2^-16, dropped)
// so absmax stays at the v-store bf16 quantization bound (0.015625).
// ---------------------------------------------------------------------------
__device__ void vproj_body(int tile, const float* __restrict__ h,
                           const float* __restrict__ Wv,
                           const float* __restrict__ bv,
                           unsigned short* __restrict__ v) {
    int lane = threadIdx.x & 63;
    int i = lane & 31, g = lane >> 5;
    int n = tile * 32 + i;
    bool nok = (n < N_O);
    const float* hrow = h + (size_t)n * 128;

    // hi-part bf16 fragments of this node's h row (B operand), kept in regs
    short8 bh[8];
    #pragma unroll
    for (int m = 0; m < 8; ++m) {
        float4 u0 = make_float4(0.f, 0.f, 0.f, 0.f), u1 = u0;
        if (nok) {
            u0 = *(const float4*)(hrow + 16 * m + 8 * g);
            u1 = *(const float4*)(hrow + 16 * m + 8 * g + 4);
        }
        union { unsigned u[4]; short8 s; } p;
        p.u[0] = pk2(u0.x, u0.y); p.u[1] = pk2(u0.z, u0.w);
        p.u[2] = pk2(u1.x, u1.y); p.u[3] = pk2(u1.z, u1.w);
        bh[m] = p.s;
    }

    #pragma unroll 1
    for (int c = 0; c < 4; ++c) {
        f32x16 acc;
        #pragma unroll
        for (int k = 0; k < 16; ++k) acc[k] = 0.f;
        #pragma unroll
        for (int m = 0; m < 8; ++m) {
            // A fragment: lane holds A[row=i][k=8g+j] = Wv[16m+8g+j][32c+i]
            const float* wp = Wv + (size_t)(16 * m + 8 * g) * 128 + 32 * c + i;
            float w[8];
            #pragma unroll
            for (int j = 0; j < 8; ++j) w[j] = wp[(size_t)j * 128];
            union { unsigned u[4]; short8 s; } wh, wl, hl;
            #pragma unroll
            for (int j = 0; j < 4; ++j) wh.u[j] = pk2(w[2 * j], w[2 * j + 1]);
            #pragma unroll
            for (int j = 0; j < 4; ++j) {
                float e0 = w[2 * j]     - __uint_as_float(wh.u[j] << 16);
                float e1 = w[2 * j + 1] - __uint_as_float(wh.u[j] & 0xffff0000u);
                wl.u[j] = pk2(e0, e1);
            }
            // h residual fragment (reload h: L1-hot, keeps VGPR peak low)
            float4 u0 = make_float4(0.f, 0.f, 0.f, 0.f), u1 = u0;
            if (nok) {
                u0 = *(const float4*)(hrow + 16 * m + 8 * g);
                u1 = *(const float4*)(hrow + 16 * m + 8 * g + 4);
            }
            float x[8] = {u0.x, u0.y, u0.z, u0.w, u1.x, u1.y, u1.z, u1.w};
            union { unsigned u[4]; short8 s; } bhp;
            bhp.s = bh[m];
            #pragma unroll
            for (int j = 0; j < 4; ++j) {
                float e0 = x[2 * j]     - __uint_as_float(bhp.u[j] << 16);
                float e1 = x[2 * j + 1] - __uint_as_float(bhp.u[j] & 0xffff0000u);
                hl.u[j] = pk2(e0, e1);
            }
            acc = __builtin_amdgcn_mfma_f32_32x32x16_bf16(wh.s, bh[m], acc, 0, 0, 0);
            acc = __builtin_amdgcn_mfma_f32_32x32x16_bf16(wh.s, hl.s,  acc, 0, 0, 0);
            acc = __builtin_amdgcn_mfma_f32_32x32x16_bf16(wl.s, bh[m], acc, 0, 0, 0);
        }
        if (nok) {
            // C layout: lane (i,g) reg r -> v[n][32c + (r&3)+8*(r>>2)+4g]
            #pragma unroll
            for (int q = 0; q < 4; ++q) {
                int vc = 32 * c + 8 * q + 4 * g;
                float4 bq = *(const float4*)(bv + vc);
                uint2 ov;
                ov.x = pk2(acc[4 * q + 0] + bq.x, acc[4 * q + 1] + bq.y);
                ov.y = pk2(acc[4 * q + 2] + bq.z, acc[4 * q + 3] + bq.w);
                *(uint2*)(v + (size_t)n * 128 + vc) = ov;
            }
        }
    }
}

// ---------------------------------------------------------------------------
// edge body (NEW: LDS-free). One wave = 32 edges. Per hidden-block b:
// GEMM1 (32x32x16) -> relu/bf16 pack -> lane-pair exchange via shfl_xor(32)
// -> 2x GEMM2 MFMA (K=32 of 128). The GEMM1 C layout and GEMM2 B layout
// differ only across the (i, i+32) lane pair: lane i owns rows 8q+{0..3},
// lane i+32 owns 8q+{4..7} of each 8-row group. Verified equal to the
// R10-proven LDS bounce (row r stored at byte 2r, read 16m+8h+{0..7}).
// ---------------------------------------------------------------------------
__device__ void edge_body(int bid, const float* __restrict__ pos_obs,
                          const float* __restrict__ pos_query,
                          const int* __restrict__ src, const int* __restrict__ dst,
                          const unsigned short* __restrict__ W1cT,
                          const unsigned short* __restrict__ W2tb,
                          const float* __restrict__ scal,
                          float* __restrict__ logitsT) {
    int t = threadIdx.x;
    int wave = t >> 6, lane = t & 63;
    int i = lane & 31, h = lane >> 5;

    short8 zero8;
    #pragma unroll
    for (int k = 0; k < 8; ++k) zero8[k] = 0;

    int e = bid * 64 + wave * 32 + i;
    int s = src[e], d = dst[e];
    float pox = pos_obs[s * 3 + 0], poy = pos_obs[s * 3 + 1], poz = pos_obs[s * 3 + 2];
    float pqx = pos_query[d * 3 + 0], pqy = pos_query[d * 3 + 1], pqz = pos_query[d * 3 + 2];
    float rx = pqx - pox, ry = pqy - poy, rz = pqz - poz;
    float dist2 = rx * rx + ry * ry + rz * rz;

    short8 bea = zero8;
    if (h == 0) {
        bea[0] = (short)f2bf(pqx); bea[1] = (short)f2bf(pqy); bea[2] = (short)f2bf(pqz);
        bea[3] = (short)f2bf(pox); bea[4] = (short)f2bf(poy); bea[5] = (short)f2bf(poz);
        bea[6] = (short)0x3F80;    // 1.0 bf16 (bias attr)
        bea[7] = 0;
    }

    f32x16 c2;
    #pragma unroll
    for (int k = 0; k < 16; ++k) c2[k] = 0.f;

    #pragma unroll
    for (int b = 0; b < 4; ++b) {
        short8 a1b = (h == 0) ? *(const short8*)(W1cT + (32 * b + i) * 8) : zero8;
        f32x16 c1;
        #pragma unroll
        for (int k = 0; k < 16; ++k) c1[k] = 0.f;
        c1 = __builtin_amdgcn_mfma_f32_32x32x16_bf16(a1b, bea, c1, 0, 0, 0);

        // relu -> bf16 pack: hw[q] = rows 32b + 8q + 4h + {0..3} of edge i
        unsigned hw[4][2], pw[4][2];
        #pragma unroll
        for (int q = 0; q < 4; ++q) {
            float x0 = fmaxf(c1[4 * q + 0], 0.f);
            float x1 = fmaxf(c1[4 * q + 1], 0.f);
            float x2 = fmaxf(c1[4 * q + 2], 0.f);
            float x3 = fmaxf(c1[4 * q + 3], 0.f);
            hw[q][0] = pk2(x0, x1);
            hw[q][1] = pk2(x2, x3);
        }
        // exchange with lane^32 partner (same edge, other 4-row half)
        #pragma unroll
        for (int q = 0; q < 4; ++q) {
            pw[q][0] = (unsigned)__shfl_xor((int)hw[q][0], 32);
            pw[q][1] = (unsigned)__shfl_xor((int)hw[q][1], 32);
        }
        #pragma unroll
        for (int mo = 0; mo < 2; ++mo) {
            int m = 2 * b + mo;
            int q0 = 2 * mo, q1 = 2 * mo + 1;
            short8 a2m = (i < 4) ? *(const short8*)(W2tb + i * 128 + m * 16 + h * 8) : zero8;
            // B frag: k = 16m + 8h + j of edge i
            union { unsigned u[4]; short8 s8; } bf;
            bf.u[0] = h ? pw[q1][0] : hw[q0][0];
            bf.u[1] = h ? pw[q1][1] : hw[q0][1];
            bf.u[2] = h ? hw[q1][0] : pw[q0][0];
            bf.u[3] = h ? hw[q1][1] : pw[q0][1];
            c2 = __builtin_amdgcn_mfma_f32_32x32x16_bf16(a2m, bf.s8, c2, 0, 0, 0);
        }
    }

    if (h == 0) {
        float pen = dist2 * scal[0];
        logitsT[0 * NE + e] = c2[0] + scal[1] - pen;
        logitsT[1 * NE + e] = c2[1] + scal[2] - pen;
        logitsT[2 * NE + e] = c2[2] + scal[3] - pen;
        logitsT[3 * NE + e] = c2[3] + scal[4] - pen;
    }
}

// ---------------------------------------------------------------------------
// fused: edge | vproj | rowptr partitioned by blockIdx (mutually
// independent). 128 threads, ZERO LDS -> occupancy now VGPR-bound only.
// ---------------------------------------------------------------------------
__global__ __launch_bounds__(128) void fused_kernel(
        const float* __restrict__ pos_obs, const float* __restrict__ pos_query,
        const int* __restrict__ src, const int* __restrict__ dst,
        const unsigned short* __restrict__ W1cT,
        const unsigned short* __restrict__ W2tb,
        const float* __restrict__ scal, float* __restrict__ logitsT,
        const float* __restrict__ h_obs, const float* __restrict__ Wv,
        const float* __restrict__ bv, unsigned short* __restrict__ vbuf,
        int* __restrict__ rp) {
    int b = blockIdx.x;
    if (b < EDGE_BLOCKS) {
        edge_body(b, pos_obs, pos_query, src, dst, W1cT, W2tb, scal, logitsT);
    } else if (b < EDGE_BLOCKS + VP_BLOCKS) {
        int tile = (b - EDGE_BLOCKS) * 2 + (threadIdx.x >> 6);
        if (tile < VP_TILES) vproj_body(tile, h_obs, Wv, bv, vbuf);
    } else {
        rowptr_body(b - EDGE_BLOCKS - VP_BLOCKS, dst, rp);
    }
}

// ---------------------------------------------------------------------------
// attn (R10-proven, verbatim): one wave per query; LDS-staged exp weights.
// ---------------------------------------------------------------------------
__global__ __launch_bounds__(256) void attn_kernel(const __hip_bfloat162* __restrict__ vb,
                                                   const float* __restrict__ logitsT,
                                                   const int* __restrict__ src,
                                                   const int* __restrict__ rp,
                                                   float* __restrict__ out) {
    __shared__ __align__(16) float wsh[4 * 4 * WCAP];   // 16896 B
    int t = threadIdx.x;
    int lane = t & 63, wave = t >> 6;
    int q = blockIdx.x * 4 + wave;
    int s0 = rp[q], s1 = rp[q + 1];
    int cnt = s1 - s0;
    int h = lane >> 4, i = lane & 15;
    const float* lp = logitsT + (size_t)h * NE;

    float m = -INFINITY;
    for (int e = s0 + i; e < s1; e += 16) m = fmaxf(m, lp[e]);
    #pragma unroll
    for (int off = 8; off; off >>= 1) m = fmaxf(m, __shfl_xor(m, off));

    float acc0 = 0.f, acc1 = 0.f, r;

    if (cnt <= 256) {
        int s0a = s0 & ~3;
        float* wpb = wsh + wave * (4 * WCAP) + h * WCAP;
        float sum = 0.f;
        for (int e = s0 + i; e < s1; e += 16) {
            float w = __expf(lp[e] - m);
            wpb[e - s0a] = w;
            sum += w;
        }
        #pragma unroll
        for (int off = 8; off; off >>= 1) sum += __shfl_xor(sum, off);
        r = 1.0f / (sum + 1e-16f);

        int e = s0;
        int e1 = (s0 + 3) & ~3; if (e1 > s1) e1 = s1;
        for (; e < e1; ++e) {
            float w = wpb[e - s0a];
            float2 f = __bfloat1622float2(vb[(size_t)src[e] * 64 + lane]);
            acc0 += w * f.x; acc1 += w * f.y;
        }
        for (; e + 4 <= s1; e += 4) {
            float4 w4 = *(const float4*)(wpb + (e - s0a));
            int4 s4 = *(const int4*)(src + e);
            float2 f0 = __bfloat1622float2(vb[(size_t)s4.x * 64 + lane]);
            float2 f1 = __bfloat1622float2(vb[(size_t)s4.y * 64 + lane]);
            float2 f2 = __bfloat1622float2(vb[(size_t)s4.z * 64 + lane]);
            float2 f3 = __bfloat1622float2(vb[(size_t)s4.w * 64 + lane]);
            acc0 += w4.x * f0.x + w4.y * f1.x + w4.z * f2.x + w4.w * f3.x;
            acc1 += w4.x * f0.y + w4.y * f1.y + w4.z * f2.y + w4.w * f3.y;
        }
        for (; e < s1; ++e) {
            float w = wpb[e - s0a];
            float2 f = __bfloat1622float2(vb[(size_t)src[e] * 64 + lane]);
            acc0 += w * f.x; acc1 += w * f.y;
        }
    } else {
        float sum = 0.f;
        for (int e = s0 + i; e < s1; e += 16) sum += __expf(lp[e] - m);
        #pragma unroll
        for (int off = 8; off; off >>= 1) sum += __shfl_xor(sum, off);
        r = 1.0f / (sum + 1e-16f);

        int e = s0;
        for (; e < s1 && (e & 3); ++e) {
            float w = __expf(lp[e] - m);
            float2 f = __bfloat1622float2(vb[(size_t)src[e] * 64 + lane]);
            acc0 += w * f.x; acc1 += w * f.y;
        }
        for (; e + 4 <= s1; e += 4) {
            float4 l4 = *(const float4*)(lp + e);
            int4 s4 = *(const int4*)(src + e);
            float w0 = __expf(l4.x - m);
            float w1 = __expf(l4.y - m);
            float w2 = __expf(l4.z - m);
            float w3 = __expf(l4.w - m);
            float2 f0 = __bfloat1622float2(vb[(size_t)s4.x * 64 + lane]);
            float2 f1 = __bfloat1622float2(vb[(size_t)s4.y * 64 + lane]);
            float2 f2 = __bfloat1622float2(vb[(size_t)s4.z * 64 + lane]);
            float2 f3 = __bfloat1622float2(vb[(size_t)s4.w * 64 + lane]);
            acc0 += w0 * f0.x + w1 * f1.x + w2 * f2.x + w3 * f3.x;
            acc1 += w0 * f0.y + w1 * f1.y + w2 * f2.y + w3 * f3.y;
        }
        for (; e < s1; ++e) {
            float w = __expf(lp[e] - m);
            float2 f = __bfloat1622float2(vb[(size_t)src[e] * 64 + lane]);
            acc0 += w * f.x; acc1 += w * f.y;
        }
    }
    *(float2*)(out + (size_t)q * 128 + lane * 2) = make_float2(acc0 * r, acc1 * r);
}

// ---------------------------------------------------------------------------
// ws layout: identical to the R1-R6/R10-proven layout (high water 38,608,768 B).
// ---------------------------------------------------------------------------
extern "C" void kernel_launch(void* const* d_in, const int* in_sizes, int n_in,
                              void* d_out, int out_size, void* d_ws, size_t ws_size,
                              hipStream_t stream) {
    const float* h_obs     = (const float*)d_in[0];
    const float* pos_obs   = (const float*)d_in[1];
    const float* pos_query = (const float*)d_in[2];
    const int*   src       = (const int*)d_in[3];
    const int*   dst       = (const int*)d_in[4];
    const float* W1        = (const float*)d_in[5];
    const float* b1        = (const float*)d_in[6];
    const float* W2        = (const float*)d_in[7];
    const float* b2        = (const float*)d_in[8];
    const float* Wv        = (const float*)d_in[9];
    const float* bv        = (const float*)d_in[10];
    const float* log_sigma = (const float*)d_in[11];
    float* out = (float*)d_out;

    char* ws = (char*)d_ws;
    int*            rp      = (int*)(ws + 0);                   // 50001 ints  (end 200,004)
    float*          scal    = (float*)(ws + 200192);            // 8 floats    (end 200,224)
    unsigned short* W1cT    = (unsigned short*)(ws + 200256);   // 1024 bf16   (end 202,304)
    unsigned short* W2tb    = (unsigned short*)(ws + 202304);   // 512 bf16    (end 203,328)
    unsigned short* vbuf    = (unsigned short*)(ws + 208640);   // 6.4M bf16   (end 13,008,640)
    float*          logitsT = (float*)(ws + 13008768);          // 6.4M floats (end 38,608,768)

    hipLaunchKernelGGL(pack_kernel, dim3(1), dim3(256), 0, stream,
                       W1, b1, W2, b2, log_sigma, W1cT, W2tb, scal);
    hipLaunchKernelGGL(fused_kernel, dim3(EDGE_BLOCKS + VP_BLOCKS + RP_BLOCKS),
                       dim3(128), 0, stream,
                       pos_obs, pos_query, src, dst, W1cT, W2tb, scal, logitsT,
                       h_obs, Wv, bv, vbuf, rp);
    hipLaunchKernelGGL(attn_kernel, dim3(N_Q / 4), dim3(256), 0, stream,
                       (const __hip_bfloat162*)vbuf, logitsT, src, rp, out);
}

// Round 2
// 244.703 us; speedup vs baseline: 1.1677x; 1.1677x over previous
//
#include <hip/hip_runtime.h>
#include <hip/hip_bf16.h>
#include <cstdint>
#include <cstddef>

#define N_O 50000
#define N_Q 50000
#define NE  1600000
// LATENT=128, HEADS=4, HEAD_DIM=32

#define EDGE_BLOCKS  (NE / 64)             // 25000 (2 waves x 32 edges, 128 thr)
#define VP_BLOCKS    ((N_O + 31) / 32)     // 1563  (32 rows per block)
#define RP_BLOCKS    ((N_Q + 128) / 128)   // 391
#define WCAP 264                           // attn LDS plane stride (floats)

// WvP planes live past the R0 high-water mark; runtime-checked.
#define WVP_OFF   38608768u
#define WVP_BYTES 65536u

typedef __attribute__((ext_vector_type(8)))  short short8;
typedef __attribute__((ext_vector_type(16))) float f32x16;

__device__ inline unsigned short f2bf(float x) {
    __hip_bfloat16 hb = __float2bfloat16(x);
    return *reinterpret_cast<unsigned short*>(&hb);
}

__device__ inline unsigned pk2(float a, float b) {
    __hip_bfloat162 t = __float22bfloat162_rn(make_float2(a, b));
    return *reinterpret_cast<unsigned*>(&t);
}

// ---------------------------------------------------------------------------
// pack: bf16 weight tensors for the MFMA edge MLP (R6/R10-proven part,
// block 0) + NEW fragment-ordered Wv hi/lo bf16 planes (blocks 1..8).
//  W1cT [128 hidden][8 attr] bf16 : attrs = [Wq+Wr (3), Wo-Wr (3), b1, 0]
//  W2tb [4 head][128 hidden] bf16
//  scal fp32: [0]=1/(2 sigma^2), [1..4]=b2
//  WvPhi/WvPlo: A-fragment order for 32x32x16 MFMA, frag-row
//  fr=(c*8+ks)*64+lane holds A[row=lane&31][k=16*ks+8*(lane>>5)+j]
//  = Wv[k][32c+row], j=0..7 contiguous (one 16B load per MFMA).
// ---------------------------------------------------------------------------
__global__ void pack_kernel(const float* __restrict__ W1, const float* __restrict__ b1,
                            const float* __restrict__ W2, const float* __restrict__ b2,
                            const float* __restrict__ log_sigma,
                            const float* __restrict__ Wv,
                            unsigned short* __restrict__ W1cT,
                            unsigned short* __restrict__ W2tb,
                            float* __restrict__ scal,
                            unsigned short* __restrict__ WvPhi,
                            unsigned short* __restrict__ WvPlo,
                            int vp_mfma) {
    int j = threadIdx.x;
    if (blockIdx.x == 0) {
        if (j < 128) {
            #pragma unroll
            for (int a = 0; a < 3; ++a) {
                W1cT[j * 8 + a]     = f2bf(W1[(3 + a) * 128 + j] + W1[a * 128 + j]); // pq coef
                W1cT[j * 8 + 3 + a] = f2bf(W1[(6 + a) * 128 + j] - W1[a * 128 + j]); // po coef
            }
            W1cT[j * 8 + 6] = f2bf(b1[j]);
            W1cT[j * 8 + 7] = 0;
            #pragma unroll
            for (int hd = 0; hd < 4; ++hd)
                W2tb[hd * 128 + j] = f2bf(W2[j * 4 + hd]);
        } else if (j == 128) {
            float sigma = expf(log_sigma[0]) + 1e-6f;
            scal[0] = 1.0f / (2.0f * sigma * sigma);
            scal[1] = b2[0]; scal[2] = b2[1]; scal[3] = b2[2]; scal[4] = b2[3];
        }
    } else if (vp_mfma) {
        // blocks 1..8: one frag-row (8 elems) per thread; 2048 frag-rows total
        int fr = (blockIdx.x - 1) * 256 + j;        // 0..2047
        int lane = fr & 63, i = lane & 31, g = lane >> 5;
        int ks = (fr >> 6) & 7, c = fr >> 9;
        #pragma unroll
        for (int e = 0; e < 8; ++e) {
            float w = Wv[(size_t)(16 * ks + 8 * g + e) * 128 + 32 * c + i];
            unsigned short hi = f2bf(w);
            float rem = w - __uint_as_float(((unsigned)hi) << 16);
            WvPhi[fr * 8 + e] = hi;
            WvPlo[fr * 8 + e] = f2bf(rem);
        }
    }
}

// ---------------------------------------------------------------------------
// rowptr body (proven, unchanged): rp[q] = lower_bound(dst,q)
// ---------------------------------------------------------------------------
__device__ void rowptr_body(int bid, const int* __restrict__ dst, int* __restrict__ rp) {
    int q = bid * 128 + threadIdx.x;
    if (q > N_Q) return;
    int lo = 0, hi = NE;
    while (lo < hi) {
        int mid = (lo + hi) >> 1;
        if (dst[mid] < q) lo = mid + 1; else hi = mid;
    }
    rp[q] = lo;
}

// ---------------------------------------------------------------------------
// vproj MFMA (NEW): v = h_obs @ Wv + bv, 32-row tile per block; the two
// waves split the 4 output col-tiles (wave w -> c in {2w, 2w+1}).
// D[vc][n]: A = pre-packed WvP hi/lo frags (ONE 16B L2-hot load each),
// B = h row hi/lo frags built once in registers (h read exactly once).
// 3-pass split keeps fp32-level accuracy (lo*lo ~ 2^-16 dropped):
//   acc += Whi*Hhi + Whi*Hlo + Wlo*Hhi
// No LDS, no syncthreads. 96 MFMA/block vs 4096 FMA/thread in fp32 path.
// ---------------------------------------------------------------------------
__device__ void vproj_mfma_body(int tile, const float* __restrict__ h,
                                const unsigned short* __restrict__ WvPhi,
                                const unsigned short* __restrict__ WvPlo,
                                const float* __restrict__ bv,
                                unsigned short* __restrict__ v) {
    int lane = threadIdx.x & 63, wave = threadIdx.x >> 6;
    int i = lane & 31, g = lane >> 5;
    int n = tile * 32 + i;
    bool nok = (n < N_O);
    const float* hrow = h + (size_t)n * 128;

    // B fragments: lane (i,g) holds h[n][16ks+8g+j], j=0..7 (hi + residual)
    short8 Bhi[8], Blo[8];
    #pragma unroll
    for (int ks = 0; ks < 8; ++ks) {
        float4 u0 = make_float4(0.f, 0.f, 0.f, 0.f), u1 = u0;
        if (nok) {
            u0 = *(const float4*)(hrow + 16 * ks + 8 * g);
            u1 = *(const float4*)(hrow + 16 * ks + 8 * g + 4);
        }
        float x[8] = {u0.x, u0.y, u0.z, u0.w, u1.x, u1.y, u1.z, u1.w};
        union { unsigned u[4]; short8 s; } ph, pl;
        #pragma unroll
        for (int p = 0; p < 4; ++p) {
            ph.u[p] = pk2(x[2 * p], x[2 * p + 1]);
            float e0 = x[2 * p]     - __uint_as_float(ph.u[p] << 16);
            float e1 = x[2 * p + 1] - __uint_as_float(ph.u[p] & 0xffff0000u);
            pl.u[p] = pk2(e0, e1);
        }
        Bhi[ks] = ph.s; Blo[ks] = pl.s;
    }

    #pragma unroll 1
    for (int cc = 0; cc < 2; ++cc) {
        int c = 2 * wave + cc;
        f32x16 acc;
        #pragma unroll
        for (int k = 0; k < 16; ++k) acc[k] = 0.f;
        #pragma unroll
        for (int ks = 0; ks < 8; ++ks) {
            int fr = (c * 8 + ks) * 64 + lane;
            short8 Ahi = *(const short8*)(WvPhi + fr * 8);
            short8 Alo = *(const short8*)(WvPlo + fr * 8);
            acc = __builtin_amdgcn_mfma_f32_32x32x16_bf16(Ahi, Bhi[ks], acc, 0, 0, 0);
            acc = __builtin_amdgcn_mfma_f32_32x32x16_bf16(Ahi, Blo[ks], acc, 0, 0, 0);
            acc = __builtin_amdgcn_mfma_f32_32x32x16_bf16(Alo, Bhi[ks], acc, 0, 0, 0);
        }
        if (nok) {
            // C layout: lane (i,g) reg 4q+s -> row vc = 32c + 8q + 4g + s
            #pragma unroll
            for (int q = 0; q < 4; ++q) {
                int vc = 32 * c + 8 * q + 4 * g;
                float4 bq = *(const float4*)(bv + vc);
                uint2 ov;
                ov.x = pk2(acc[4 * q + 0] + bq.x, acc[4 * q + 1] + bq.y);
                ov.y = pk2(acc[4 * q + 2] + bq.z, acc[4 * q + 3] + bq.w);
                *(uint2*)(v + (size_t)n * 128 + vc) = ov;
            }
        }
    }
}

// ---------------------------------------------------------------------------
// vproj fp32 fallback (R0-proven, verbatim): used only if ws_size is too
// tight for the WvP planes. LDS 32*132*4 = 16896 B.
// ---------------------------------------------------------------------------
__device__ void vproj_f32_body(int bid, const float* __restrict__ h,
                               const float* __restrict__ Wv,
                               const float* __restrict__ bv,
                               unsigned short* __restrict__ v,
                               float* Ash /* 32*132 floats */) {
    int t = threadIdx.x;          // 0..127
    int n0 = bid * 32;
    #pragma unroll
    for (int rep = 0; rep < 8; ++rep) {
        int idx = rep * 128 + t;           // flat over [32][32] float4s
        int row = idx >> 5, c4 = (idx & 31) * 4;
        float4 val = make_float4(0.f, 0.f, 0.f, 0.f);
        if (n0 + row < N_O) val = *(const float4*)(h + (size_t)(n0 + row) * 128 + c4);
        float* d = &Ash[row * 132 + c4];
        d[0] = val.x; d[1] = val.y; d[2] = val.z; d[3] = val.w;
    }
    __syncthreads();

    int cg = t & 15, rg = t >> 4;          // 16 col groups x 8 row groups
    int c0 = cg * 8, r0 = rg * 4;
    float acc[4][8];
    #pragma unroll
    for (int i = 0; i < 4; ++i)
        #pragma unroll
        for (int j = 0; j < 8; ++j) acc[i][j] = 0.f;

    const float4* Wv4 = (const float4*)Wv;
    for (int k = 0; k < 128; ++k) {
        float4 b0 = Wv4[k * 32 + cg * 2];
        float4 b1v = Wv4[k * 32 + cg * 2 + 1];
        float bb[8] = {b0.x, b0.y, b0.z, b0.w, b1v.x, b1v.y, b1v.z, b1v.w};
        #pragma unroll
        for (int i = 0; i < 4; ++i) {
            float a = Ash[(r0 + i) * 132 + k];
            #pragma unroll
            for (int j = 0; j < 8; ++j) acc[i][j] += a * bb[j];
        }
    }

    float bvv[8];
    #pragma unroll
    for (int j = 0; j < 8; ++j) bvv[j] = bv[c0 + j];
    #pragma unroll
    for (int i = 0; i < 4; ++i) {
        int n = n0 + r0 + i;
        if (n < N_O) {
            uint4 o;
            o.x = pk2(acc[i][0] + bvv[0], acc[i][1] + bvv[1]);
            o.y = pk2(acc[i][2] + bvv[2], acc[i][3] + bvv[3]);
            o.z = pk2(acc[i][4] + bvv[4], acc[i][5] + bvv[5]);
            o.w = pk2(acc[i][6] + bvv[6], acc[i][7] + bvv[7]);
            *(uint4*)(v + (size_t)n * 128 + c0) = o;
        }
    }
}

// ---------------------------------------------------------------------------
// edge body (R10-proven, verbatim revert): one wave = 32 edges.
// GEMM1 (4x 32x32x16, independent) -> relu/bf16 -> per-wave LDS tile
// [32][264 B] -> GEMM2 (8x 32x32x16, K=128). 2 waves/block, LDS 16896 B.
// ---------------------------------------------------------------------------
__device__ void edge_body(int bid, const float* __restrict__ pos_obs,
                          const float* __restrict__ pos_query,
                          const int* __restrict__ src, const int* __restrict__ dst,
                          const unsigned short* __restrict__ W1cT,
                          const unsigned short* __restrict__ W2tb,
                          const float* __restrict__ scal,
                          float* __restrict__ logitsT,
                          unsigned char* smem /* 2*8448 B */) {
    int t = threadIdx.x;
    int wave = t >> 6, lane = t & 63;
    int i = lane & 31, h = lane >> 5;
    unsigned char* myrow = smem + wave * 8448 + i * 264;

    short8 zero8;
    #pragma unroll
    for (int k = 0; k < 8; ++k) zero8[k] = 0;

    short8 a1[4];
    #pragma unroll
    for (int b = 0; b < 4; ++b)
        a1[b] = (h == 0) ? *(const short8*)(W1cT + (32 * b + i) * 8) : zero8;

    short8 a2[8];
    #pragma unroll
    for (int m = 0; m < 8; ++m)
        a2[m] = (i < 4) ? *(const short8*)(W2tb + i * 128 + m * 16 + h * 8) : zero8;

    int e = bid * 64 + wave * 32 + i;
    int s = src[e], d = dst[e];
    float pox = pos_obs[s * 3 + 0], poy = pos_obs[s * 3 + 1], poz = pos_obs[s * 3 + 2];
    float pqx = pos_query[d * 3 + 0], pqy = pos_query[d * 3 + 1], pqz = pos_query[d * 3 + 2];
    float rx = pqx - pox, ry = pqy - poy, rz = pqz - poz;
    float dist2 = rx * rx + ry * ry + rz * rz;

    short8 bea = zero8;
    if (h == 0) {
        bea[0] = (short)f2bf(pqx); bea[1] = (short)f2bf(pqy); bea[2] = (short)f2bf(pqz);
        bea[3] = (short)f2bf(pox); bea[4] = (short)f2bf(poy); bea[5] = (short)f2bf(poz);
        bea[6] = (short)0x3F80;    // 1.0 bf16 (bias attr)
        bea[7] = 0;
    }

    // GEMM1
    f32x16 c1[4];
    #pragma unroll
    for (int b = 0; b < 4; ++b) {
        #pragma unroll
        for (int k = 0; k < 16; ++k) c1[b][k] = 0.0f;
        c1[b] = __builtin_amdgcn_mfma_f32_32x32x16_bf16(a1[b], bea, c1[b], 0, 0, 0);
    }

    // relu -> bf16 -> LDS  (reg r+4s -> hidden 32b + 8s + 4h + r)
    #pragma unroll
    for (int b = 0; b < 4; ++b) {
        #pragma unroll
        for (int s_ = 0; s_ < 4; ++s_) {
            float x0 = fmaxf(c1[b][4 * s_ + 0], 0.f);
            float x1 = fmaxf(c1[b][4 * s_ + 1], 0.f);
            float x2 = fmaxf(c1[b][4 * s_ + 2], 0.f);
            float x3 = fmaxf(c1[b][4 * s_ + 3], 0.f);
            uint2 w;
            w.x = pk2(x0, x1);
            w.y = pk2(x2, x3);
            *(uint2*)(myrow + 64 * b + 16 * s_ + 8 * h) = w;
        }
    }
    // same-wave LDS RAW: compiler inserts lgkmcnt wait; no cross-wave sharing.

    // GEMM2
    f32x16 c2;
    #pragma unroll
    for (int k = 0; k < 16; ++k) c2[k] = 0.0f;
    #pragma unroll
    for (int m = 0; m < 8; ++m) {
        uint2 lo = *(const uint2*)(myrow + 32 * m + 16 * h);
        uint2 hi = *(const uint2*)(myrow + 32 * m + 16 * h + 8);
        union { unsigned int u[4]; short8 s; } bf;
        bf.u[0] = lo.x; bf.u[1] = lo.y; bf.u[2] = hi.x; bf.u[3] = hi.y;
        c2 = __builtin_amdgcn_mfma_f32_32x32x16_bf16(a2[m], bf.s, c2, 0, 0, 0);
    }

    if (h == 0) {
        float pen = dist2 * scal[0];
        logitsT[0 * NE + e] = c2[0] + scal[1] - pen;
        logitsT[1 * NE + e] = c2[1] + scal[2] - pen;
        logitsT[2 * NE + e] = c2[2] + scal[3] - pen;
        logitsT[3 * NE + e] = c2[3] + scal[4] - pen;
    }
}

// ---------------------------------------------------------------------------
// fused: edge | vproj | rowptr partitioned by blockIdx (mutually
// independent). 128 threads, 16896 B LDS (edge + fp32-fallback only).
// ---------------------------------------------------------------------------
__global__ __launch_bounds__(128) void fused_kernel(
        const float* __restrict__ pos_obs, const float* __restrict__ pos_query,
        const int* __restrict__ src, const int* __restrict__ dst,
        const unsigned short* __restrict__ W1cT,
        const unsigned short* __restrict__ W2tb,
        const float* __restrict__ scal, float* __restrict__ logitsT,
        const float* __restrict__ h_obs, const float* __restrict__ Wv,
        const float* __restrict__ bv, unsigned short* __restrict__ vbuf,
        int* __restrict__ rp,
        const unsigned short* __restrict__ WvPhi,
        const unsigned short* __restrict__ WvPlo,
        int vp_mfma) {
    __shared__ __align__(16) unsigned char smem[16896];  // 2*8448 == 32*132*4
    int b = blockIdx.x;
    if (b < EDGE_BLOCKS) {
        edge_body(b, pos_obs, pos_query, src, dst, W1cT, W2tb, scal, logitsT, smem);
    } else if (b < EDGE_BLOCKS + VP_BLOCKS) {
        int tile = b - EDGE_BLOCKS;
        if (vp_mfma) vproj_mfma_body(tile, h_obs, WvPhi, WvPlo, bv, vbuf);
        else         vproj_f32_body(tile, h_obs, Wv, bv, vbuf, (float*)smem);
    } else {
        rowptr_body(b - EDGE_BLOCKS - VP_BLOCKS, dst, rp);
    }
}

// ---------------------------------------------------------------------------
// attn (R10-proven, verbatim): one wave per query; LDS-staged exp weights.
// ---------------------------------------------------------------------------
__global__ __launch_bounds__(256) void attn_kernel(const __hip_bfloat162* __restrict__ vb,
                                                   const float* __restrict__ logitsT,
                                                   const int* __restrict__ src,
                                                   const int* __restrict__ rp,
                                                   float* __restrict__ out) {
    __shared__ __align__(16) float wsh[4 * 4 * WCAP];   // 16896 B
    int t = threadIdx.x;
    int lane = t & 63, wave = t >> 6;
    int q = blockIdx.x * 4 + wave;
    int s0 = rp[q], s1 = rp[q + 1];
    int cnt = s1 - s0;
    int h = lane >> 4, i = lane & 15;
    const float* lp = logitsT + (size_t)h * NE;

    float m = -INFINITY;
    for (int e = s0 + i; e < s1; e += 16) m = fmaxf(m, lp[e]);
    #pragma unroll
    for (int off = 8; off; off >>= 1) m = fmaxf(m, __shfl_xor(m, off));

    float acc0 = 0.f, acc1 = 0.f, r;

    if (cnt <= 256) {
        int s0a = s0 & ~3;
        float* wpb = wsh + wave * (4 * WCAP) + h * WCAP;
        float sum = 0.f;
        for (int e = s0 + i; e < s1; e += 16) {
            float w = __expf(lp[e] - m);
            wpb[e - s0a] = w;
            sum += w;
        }
        #pragma unroll
        for (int off = 8; off; off >>= 1) sum += __shfl_xor(sum, off);
        r = 1.0f / (sum + 1e-16f);

        int e = s0;
        int e1 = (s0 + 3) & ~3; if (e1 > s1) e1 = s1;
        for (; e < e1; ++e) {
            float w = wpb[e - s0a];
            float2 f = __bfloat1622float2(vb[(size_t)src[e] * 64 + lane]);
            acc0 += w * f.x; acc1 += w * f.y;
        }
        for (; e + 4 <= s1; e += 4) {
            float4 w4 = *(const float4*)(wpb + (e - s0a));
            int4 s4 = *(const int4*)(src + e);
            float2 f0 = __bfloat1622float2(vb[(size_t)s4.x * 64 + lane]);
            float2 f1 = __bfloat1622float2(vb[(size_t)s4.y * 64 + lane]);
            float2 f2 = __bfloat1622float2(vb[(size_t)s4.z * 64 + lane]);
            float2 f3 = __bfloat1622float2(vb[(size_t)s4.w * 64 + lane]);
            acc0 += w4.x * f0.x + w4.y * f1.x + w4.z * f2.x + w4.w * f3.x;
            acc1 += w4.x * f0.y + w4.y * f1.y + w4.z * f2.y + w4.w * f3.y;
        }
        for (; e < s1; ++e) {
            float w = wpb[e - s0a];
            float2 f = __bfloat1622float2(vb[(size_t)src[e] * 64 + lane]);
            acc0 += w * f.x; acc1 += w * f.y;
        }
    } else {
        float sum = 0.f;
        for (int e = s0 + i; e < s1; e += 16) sum += __expf(lp[e] - m);
        #pragma unroll
        for (int off = 8; off; off >>= 1) sum += __shfl_xor(sum, off);
        r = 1.0f / (sum + 1e-16f);

        int e = s0;
        for (; e < s1 && (e & 3); ++e) {
            float w = __expf(lp[e] - m);
            float2 f = __bfloat1622float2(vb[(size_t)src[e] * 64 + lane]);
            acc0 += w * f.x; acc1 += w * f.y;
        }
        for (; e + 4 <= s1; e += 4) {
            float4 l4 = *(const float4*)(lp + e);
            int4 s4 = *(const int4*)(src + e);
            float w0 = __expf(l4.x - m);
            float w1 = __expf(l4.y - m);
            float w2 = __expf(l4.z - m);
            float w3 = __expf(l4.w - m);
            float2 f0 = __bfloat1622float2(vb[(size_t)s4.x * 64 + lane]);
            float2 f1 = __bfloat1622float2(vb[(size_t)s4.y * 64 + lane]);
            float2 f2 = __bfloat1622float2(vb[(size_t)s4.z * 64 + lane]);
            float2 f3 = __bfloat1622float2(vb[(size_t)s4.w * 64 + lane]);
            acc0 += w0 * f0.x + w1 * f1.x + w2 * f2.x + w3 * f3.x;
            acc1 += w0 * f0.y + w1 * f1.y + w2 * f2.y + w3 * f3.y;
        }
        for (; e < s1; ++e) {
            float w = __expf(lp[e] - m);
            float2 f = __bfloat1622float2(vb[(size_t)src[e] * 64 + lane]);
            acc0 += w * f.x; acc1 += w * f.y;
        }
    }
    *(float2*)(out + (size_t)q * 128 + lane * 2) = make_float2(acc0 * r, acc1 * r);
}

// ---------------------------------------------------------------------------
// ws layout: R0-proven layout; WvP planes appended past the high-water mark
// only if ws_size allows (runtime check with fp32-vproj fallback).
// ---------------------------------------------------------------------------
extern "C" void kernel_launch(void* const* d_in, const int* in_sizes, int n_in,
                              void* d_out, int out_size, void* d_ws, size_t ws_size,
                              hipStream_t stream) {
    const float* h_obs     = (const float*)d_in[0];
    const float* pos_obs   = (const float*)d_in[1];
    const float* pos_query = (const float*)d_in[2];
    const int*   src       = (const int*)d_in[3];
    const int*   dst       = (const int*)d_in[4];
    const float* W1        = (const float*)d_in[5];
    const float* b1        = (const float*)d_in[6];
    const float* W2        = (const float*)d_in[7];
    const float* b2        = (const float*)d_in[8];
    const float* Wv        = (const float*)d_in[9];
    const float* bv        = (const float*)d_in[10];
    const float* log_sigma = (const float*)d_in[11];
    float* out = (float*)d_out;

    char* ws = (char*)d_ws;
    int*            rp      = (int*)(ws + 0);                   // 50001 ints  (end 200,004)
    float*          scal    = (float*)(ws + 200192);            // 8 floats    (end 200,224)
    unsigned short* W1cT    = (unsigned short*)(ws + 200256);   // 1024 bf16   (end 202,304)
    unsigned short* W2tb    = (unsigned short*)(ws + 202304);   // 512 bf16    (end 203,328)
    unsigned short* vbuf    = (unsigned short*)(ws + 208640);   // 6.4M bf16   (end 13,008,640)
    float*          logitsT = (float*)(ws + 13008768);          // 6.4M floats (end 38,608,768)
    unsigned short* WvPhi   = (unsigned short*)(ws + WVP_OFF);           // 32 KB
    unsigned short* WvPlo   = (unsigned short*)(ws + WVP_OFF + 32768);   // 32 KB

    int vp_mfma = (ws_size >= (size_t)WVP_OFF + WVP_BYTES) ? 1 : 0;

    hipLaunchKernelGGL(pack_kernel, dim3(9), dim3(256), 0, stream,
                       W1, b1, W2, b2, log_sigma, Wv, W1cT, W2tb, scal,
                       WvPhi, WvPlo, vp_mfma);
    hipLaunchKernelGGL(fused_kernel, dim3(EDGE_BLOCKS + VP_BLOCKS + RP_BLOCKS),
                       dim3(128), 0, stream,
                       pos_obs, pos_query, src, dst, W1cT, W2tb, scal, logitsT,
                       h_obs, Wv, bv, vbuf, rp, WvPhi, WvPlo, vp_mfma);
    hipLaunchKernelGGL(attn_kernel, dim3(N_Q / 4), dim3(256), 0, stream,
                       (const __hip_bfloat162*)vbuf, logitsT, src, rp, out);
}

// Round 3
// 207.822 us; speedup vs baseline: 1.3749x; 1.1775x over previous
//
#include <hip/hip_runtime.h>
#include <hip/hip_bf16.h>
#include <cstdint>
#include <cstddef>

#define N_O 50000
#define N_Q 50000
#define NE  1600000
// LATENT=128, HEADS=4, HEAD_DIM=32

#define EDGE_BLOCKS  (NE / 128)            // 12500 (2 waves x 64 edges, 128 thr)
#define VP_BLOCKS    ((N_O + 31) / 32)     // 1563  (32 rows per block)
#define RP_BLOCKS    ((N_Q + 128) / 128)   // 391
#define WCAP 264                           // attn LDS plane stride (floats)

// WvP planes live past the R0 high-water mark; runtime-checked.
#define WVP_OFF   38608768u
#define WVP_BYTES 65536u

typedef __attribute__((ext_vector_type(8)))  short short8;
typedef __attribute__((ext_vector_type(16))) float f32x16;

__device__ inline unsigned short f2bf(float x) {
    __hip_bfloat16 hb = __float2bfloat16(x);
    return *reinterpret_cast<unsigned short*>(&hb);
}

__device__ inline unsigned pk2(float a, float b) {
    __hip_bfloat162 t = __float22bfloat162_rn(make_float2(a, b));
    return *reinterpret_cast<unsigned*>(&t);
}

// ---------------------------------------------------------------------------
// pack (R2-proven, unchanged): block 0 = edge-MLP weights; blocks 1..8 =
// fragment-ordered Wv hi/lo bf16 planes for the MFMA vproj.
// ---------------------------------------------------------------------------
__global__ void pack_kernel(const float* __restrict__ W1, const float* __restrict__ b1,
                            const float* __restrict__ W2, const float* __restrict__ b2,
                            const float* __restrict__ log_sigma,
                            const float* __restrict__ Wv,
                            unsigned short* __restrict__ W1cT,
                            unsigned short* __restrict__ W2tb,
                            float* __restrict__ scal,
                            unsigned short* __restrict__ WvPhi,
                            unsigned short* __restrict__ WvPlo,
                            int vp_mfma) {
    int j = threadIdx.x;
    if (blockIdx.x == 0) {
        if (j < 128) {
            #pragma unroll
            for (int a = 0; a < 3; ++a) {
                W1cT[j * 8 + a]     = f2bf(W1[(3 + a) * 128 + j] + W1[a * 128 + j]); // pq coef
                W1cT[j * 8 + 3 + a] = f2bf(W1[(6 + a) * 128 + j] - W1[a * 128 + j]); // po coef
            }
            W1cT[j * 8 + 6] = f2bf(b1[j]);
            W1cT[j * 8 + 7] = 0;
            #pragma unroll
            for (int hd = 0; hd < 4; ++hd)
                W2tb[hd * 128 + j] = f2bf(W2[j * 4 + hd]);
        } else if (j == 128) {
            float sigma = expf(log_sigma[0]) + 1e-6f;
            scal[0] = 1.0f / (2.0f * sigma * sigma);
            scal[1] = b2[0]; scal[2] = b2[1]; scal[3] = b2[2]; scal[4] = b2[3];
        }
    } else if (vp_mfma) {
        // blocks 1..8: one frag-row (8 elems) per thread; 2048 frag-rows total
        int fr = (blockIdx.x - 1) * 256 + j;        // 0..2047
        int lane = fr & 63, i = lane & 31, g = lane >> 5;
        int ks = (fr >> 6) & 7, c = fr >> 9;
        #pragma unroll
        for (int e = 0; e < 8; ++e) {
            float w = Wv[(size_t)(16 * ks + 8 * g + e) * 128 + 32 * c + i];
            unsigned short hi = f2bf(w);
            float rem = w - __uint_as_float(((unsigned)hi) << 16);
            WvPhi[fr * 8 + e] = hi;
            WvPlo[fr * 8 + e] = f2bf(rem);
        }
    }
}

// ---------------------------------------------------------------------------
// rowptr body (proven, unchanged): rp[q] = lower_bound(dst,q)
// ---------------------------------------------------------------------------
__device__ void rowptr_body(int bid, const int* __restrict__ dst, int* __restrict__ rp) {
    int q = bid * 128 + threadIdx.x;
    if (q > N_Q) return;
    int lo = 0, hi = NE;
    while (lo < hi) {
        int mid = (lo + hi) >> 1;
        if (dst[mid] < q) lo = mid + 1; else hi = mid;
    }
    rp[q] = lo;
}

// ---------------------------------------------------------------------------
// vproj MFMA (R2-proven, unchanged): v = h_obs @ Wv + bv, 32-row tile per
// block, waves split output col-tiles, pre-packed A frags, 3-pass hi/lo.
// ---------------------------------------------------------------------------
__device__ void vproj_mfma_body(int tile, const float* __restrict__ h,
                                const unsigned short* __restrict__ WvPhi,
                                const unsigned short* __restrict__ WvPlo,
                                const float* __restrict__ bv,
                                unsigned short* __restrict__ v) {
    int lane = threadIdx.x & 63, wave = threadIdx.x >> 6;
    int i = lane & 31, g = lane >> 5;
    int n = tile * 32 + i;
    bool nok = (n < N_O);
    const float* hrow = h + (size_t)n * 128;

    short8 Bhi[8], Blo[8];
    #pragma unroll
    for (int ks = 0; ks < 8; ++ks) {
        float4 u0 = make_float4(0.f, 0.f, 0.f, 0.f), u1 = u0;
        if (nok) {
            u0 = *(const float4*)(hrow + 16 * ks + 8 * g);
            u1 = *(const float4*)(hrow + 16 * ks + 8 * g + 4);
        }
        float x[8] = {u0.x, u0.y, u0.z, u0.w, u1.x, u1.y, u1.z, u1.w};
        union { unsigned u[4]; short8 s; } ph, pl;
        #pragma unroll
        for (int p = 0; p < 4; ++p) {
            ph.u[p] = pk2(x[2 * p], x[2 * p + 1]);
            float e0 = x[2 * p]     - __uint_as_float(ph.u[p] << 16);
            float e1 = x[2 * p + 1] - __uint_as_float(ph.u[p] & 0xffff0000u);
            pl.u[p] = pk2(e0, e1);
        }
        Bhi[ks] = ph.s; Blo[ks] = pl.s;
    }

    #pragma unroll 1
    for (int cc = 0; cc < 2; ++cc) {
        int c = 2 * wave + cc;
        f32x16 acc;
        #pragma unroll
        for (int k = 0; k < 16; ++k) acc[k] = 0.f;
        #pragma unroll
        for (int ks = 0; ks < 8; ++ks) {
            int fr = (c * 8 + ks) * 64 + lane;
            short8 Ahi = *(const short8*)(WvPhi + fr * 8);
            short8 Alo = *(const short8*)(WvPlo + fr * 8);
            acc = __builtin_amdgcn_mfma_f32_32x32x16_bf16(Ahi, Bhi[ks], acc, 0, 0, 0);
            acc = __builtin_amdgcn_mfma_f32_32x32x16_bf16(Ahi, Blo[ks], acc, 0, 0, 0);
            acc = __builtin_amdgcn_mfma_f32_32x32x16_bf16(Alo, Bhi[ks], acc, 0, 0, 0);
        }
        if (nok) {
            #pragma unroll
            for (int q = 0; q < 4; ++q) {
                int vc = 32 * c + 8 * q + 4 * g;
                float4 bq = *(const float4*)(bv + vc);
                uint2 ov;
                ov.x = pk2(acc[4 * q + 0] + bq.x, acc[4 * q + 1] + bq.y);
                ov.y = pk2(acc[4 * q + 2] + bq.z, acc[4 * q + 3] + bq.w);
                *(uint2*)(v + (size_t)n * 128 + vc) = ov;
            }
        }
    }
}

// ---------------------------------------------------------------------------
// vproj fp32 fallback (R0-proven, verbatim): only if ws_size too tight.
// ---------------------------------------------------------------------------
__device__ void vproj_f32_body(int bid, const float* __restrict__ h,
                               const float* __restrict__ Wv,
                               const float* __restrict__ bv,
                               unsigned short* __restrict__ v,
                               float* Ash /* 32*132 floats */) {
    int t = threadIdx.x;          // 0..127
    int n0 = bid * 32;
    #pragma unroll
    for (int rep = 0; rep < 8; ++rep) {
        int idx = rep * 128 + t;
        int row = idx >> 5, c4 = (idx & 31) * 4;
        float4 val = make_float4(0.f, 0.f, 0.f, 0.f);
        if (n0 + row < N_O) val = *(const float4*)(h + (size_t)(n0 + row) * 128 + c4);
        float* d = &Ash[row * 132 + c4];
        d[0] = val.x; d[1] = val.y; d[2] = val.z; d[3] = val.w;
    }
    __syncthreads();

    int cg = t & 15, rg = t >> 4;
    int c0 = cg * 8, r0 = rg * 4;
    float acc[4][8];
    #pragma unroll
    for (int i = 0; i < 4; ++i)
        #pragma unroll
        for (int j = 0; j < 8; ++j) acc[i][j] = 0.f;

    const float4* Wv4 = (const float4*)Wv;
    for (int k = 0; k < 128; ++k) {
        float4 b0 = Wv4[k * 32 + cg * 2];
        float4 b1v = Wv4[k * 32 + cg * 2 + 1];
        float bb[8] = {b0.x, b0.y, b0.z, b0.w, b1v.x, b1v.y, b1v.z, b1v.w};
        #pragma unroll
        for (int i = 0; i < 4; ++i) {
            float a = Ash[(r0 + i) * 132 + k];
            #pragma unroll
            for (int j = 0; j < 8; ++j) acc[i][j] += a * bb[j];
        }
    }

    float bvv[8];
    #pragma unroll
    for (int j = 0; j < 8; ++j) bvv[j] = bv[c0 + j];
    #pragma unroll
    for (int i = 0; i < 4; ++i) {
        int n = n0 + r0 + i;
        if (n < N_O) {
            uint4 o;
            o.x = pk2(acc[i][0] + bvv[0], acc[i][1] + bvv[1]);
            o.y = pk2(acc[i][2] + bvv[2], acc[i][3] + bvv[3]);
            o.z = pk2(acc[i][4] + bvv[4], acc[i][5] + bvv[5]);
            o.w = pk2(acc[i][6] + bvv[6], acc[i][7] + bvv[7]);
            *(uint4*)(v + (size_t)n * 128 + c0) = o;
        }
    }
}

// ---------------------------------------------------------------------------
// edge body v2: one wave = 64 DISTINCT edges (each lane gathers its own
// edge -> no duplicated scattered loads, 2x ILP, half the waves).
// Lower-half lanes' packed attrs form B-frag A; upper half's attrs arrive
// via shfl_xor(32) to form B-frag B. The two 32-edge sets run the proven
// GEMM1 -> LDS bounce -> GEMM2 pipeline sequentially, reusing the same
// 8448 B/wave LDS tile (in-order per-wave DS ops make the WAR safe, same
// assumption as the proven same-wave RAW). GEMM2 accumulation split into
// two independent 4-chains to halve exposed MFMA latency. All 64 lanes
// store their own edge's 4 logits (set-B heads shuffled up) -> coalesced.
// ---------------------------------------------------------------------------
__device__ void edge_body(int bid, const float* __restrict__ pos_obs,
                          const float* __restrict__ pos_query,
                          const int* __restrict__ src, const int* __restrict__ dst,
                          const unsigned short* __restrict__ W1cT,
                          const unsigned short* __restrict__ W2tb,
                          const float* __restrict__ scal,
                          float* __restrict__ logitsT,
                          unsigned char* smem /* 2*8448 B */) {
    int t = threadIdx.x;
    int wave = t >> 6, lane = t & 63;
    int i = lane & 31, h = lane >> 5;
    unsigned char* myrow = smem + wave * 8448 + i * 264;

    short8 zero8;
    #pragma unroll
    for (int k = 0; k < 8; ++k) zero8[k] = 0;

    // own-edge gathers (all issued upfront; the only long-latency chain)
    int e = bid * 128 + wave * 64 + lane;
    int s = src[e], d = dst[e];
    float pox = pos_obs[s * 3 + 0], poy = pos_obs[s * 3 + 1], poz = pos_obs[s * 3 + 2];
    float pqx = pos_query[d * 3 + 0], pqy = pos_query[d * 3 + 1], pqz = pos_query[d * 3 + 2];
    float rx = pqx - pox, ry = pqy - poy, rz = pqz - poz;
    float dist2 = rx * rx + ry * ry + rz * rz;

    // packed edge attrs: [pqx,pqy][pqz,pox][poy,poz][1.0,0]
    unsigned pk[4];
    pk[0] = pk2(pqx, pqy);
    pk[1] = pk2(pqz, pox);
    pk[2] = pk2(poy, poz);
    pk[3] = 0x00003F80u;

    unsigned pb[4];
    #pragma unroll
    for (int p = 0; p < 4; ++p) pb[p] = (unsigned)__shfl_xor((int)pk[p], 32);

    union { unsigned u[4]; short8 s8; } beaA, beaB;
    #pragma unroll
    for (int p = 0; p < 4; ++p) {
        beaA.u[p] = h ? 0u : pk[p];     // set A: edges base+0..31
        beaB.u[p] = h ? 0u : pb[p];     // set B: edges base+32..63
    }

    short8 a1[4];
    #pragma unroll
    for (int b = 0; b < 4; ++b)
        a1[b] = (h == 0) ? *(const short8*)(W1cT + (32 * b + i) * 8) : zero8;

    short8 a2[8];
    #pragma unroll
    for (int m = 0; m < 8; ++m)
        a2[m] = (i < 4) ? *(const short8*)(W2tb + i * 128 + m * 16 + h * 8) : zero8;

    float headA[4], headB[4];

    #pragma unroll
    for (int set = 0; set < 2; ++set) {
        const short8 bea = set ? beaB.s8 : beaA.s8;

        // GEMM1: 4 independent MFMAs
        f32x16 c1[4];
        #pragma unroll
        for (int b = 0; b < 4; ++b) {
            #pragma unroll
            for (int k = 0; k < 16; ++k) c1[b][k] = 0.0f;
            c1[b] = __builtin_amdgcn_mfma_f32_32x32x16_bf16(a1[b], bea, c1[b], 0, 0, 0);
        }

        // relu -> bf16 -> LDS (proven layout: hidden 32b+8s+4h+r at 64b+16s+8h)
        #pragma unroll
        for (int b = 0; b < 4; ++b) {
            #pragma unroll
            for (int s_ = 0; s_ < 4; ++s_) {
                float x0 = fmaxf(c1[b][4 * s_ + 0], 0.f);
                float x1 = fmaxf(c1[b][4 * s_ + 1], 0.f);
                float x2 = fmaxf(c1[b][4 * s_ + 2], 0.f);
                float x3 = fmaxf(c1[b][4 * s_ + 3], 0.f);
                uint2 w;
                w.x = pk2(x0, x1);
                w.y = pk2(x2, x3);
                *(uint2*)(myrow + 64 * b + 16 * s_ + 8 * h) = w;
            }
        }

        // GEMM2: two independent 4-chains (halve exposed MFMA latency)
        f32x16 cx, cy;
        #pragma unroll
        for (int k = 0; k < 16; ++k) { cx[k] = 0.0f; cy[k] = 0.0f; }
        #pragma unroll
        for (int m = 0; m < 8; m += 2) {
            uint2 lo0 = *(const uint2*)(myrow + 32 * m + 16 * h);
            uint2 hi0 = *(const uint2*)(myrow + 32 * m + 16 * h + 8);
            uint2 lo1 = *(const uint2*)(myrow + 32 * (m + 1) + 16 * h);
            uint2 hi1 = *(const uint2*)(myrow + 32 * (m + 1) + 16 * h + 8);
            union { unsigned int u[4]; short8 s; } b0, b1u;
            b0.u[0] = lo0.x; b0.u[1] = lo0.y; b0.u[2] = hi0.x; b0.u[3] = hi0.y;
            b1u.u[0] = lo1.x; b1u.u[1] = lo1.y; b1u.u[2] = hi1.x; b1u.u[3] = hi1.y;
            cx = __builtin_amdgcn_mfma_f32_32x32x16_bf16(a2[m],     b0.s,  cx, 0, 0, 0);
            cy = __builtin_amdgcn_mfma_f32_32x32x16_bf16(a2[m + 1], b1u.s, cy, 0, 0, 0);
        }
        float* hd = set ? headB : headA;
        #pragma unroll
        for (int r = 0; r < 4; ++r) hd[r] = cx[r] + cy[r];
    }

    // store: every lane writes its OWN edge's 4 logits (coalesced 256B/plane)
    float pen = dist2 * scal[0];
    #pragma unroll
    for (int r = 0; r < 4; ++r) {
        float vB = __shfl_xor(headB[r], 32);       // lane 32+i <- lane i's set-B head
        float val = (h ? vB : headA[r]) + scal[1 + r] - pen;
        logitsT[(size_t)r * NE + e] = val;
    }
}

// ---------------------------------------------------------------------------
// fused: edge | vproj | rowptr partitioned by blockIdx. 128 threads,
// 16896 B LDS. (128,4): pin VGPR <=128 so edge's extra live state can't
// fall off the 4-waves/SIMD cliff.
// ---------------------------------------------------------------------------
__global__ __launch_bounds__(128, 4) void fused_kernel(
        const float* __restrict__ pos_obs, const float* __restrict__ pos_query,
        const int* __restrict__ src, const int* __restrict__ dst,
        const unsigned short* __restrict__ W1cT,
        const unsigned short* __restrict__ W2tb,
        const float* __restrict__ scal, float* __restrict__ logitsT,
        const float* __restrict__ h_obs, const float* __restrict__ Wv,
        const float* __restrict__ bv, unsigned short* __restrict__ vbuf,
        int* __restrict__ rp,
        const unsigned short* __restrict__ WvPhi,
        const unsigned short* __restrict__ WvPlo,
        int vp_mfma) {
    __shared__ __align__(16) unsigned char smem[16896];  // 2*8448 == 32*132*4
    int b = blockIdx.x;
    if (b < EDGE_BLOCKS) {
        edge_body(b, pos_obs, pos_query, src, dst, W1cT, W2tb, scal, logitsT, smem);
    } else if (b < EDGE_BLOCKS + VP_BLOCKS) {
        int tile = b - EDGE_BLOCKS;
        if (vp_mfma) vproj_mfma_body(tile, h_obs, WvPhi, WvPlo, bv, vbuf);
        else         vproj_f32_body(tile, h_obs, Wv, bv, vbuf, (float*)smem);
    } else {
        rowptr_body(b - EDGE_BLOCKS - VP_BLOCKS, dst, rp);
    }
}

// ---------------------------------------------------------------------------
// attn: one wave per query; LDS-staged exp weights (proven structure).
// v-gather pipeline deepened 4 -> 8 outstanding row loads per iteration.
// ---------------------------------------------------------------------------
__global__ __launch_bounds__(256) void attn_kernel(const __hip_bfloat162* __restrict__ vb,
                                                   const float* __restrict__ logitsT,
                                                   const int* __restrict__ src,
                                                   const int* __restrict__ rp,
                                                   float* __restrict__ out) {
    __shared__ __align__(16) float wsh[4 * 4 * WCAP];   // 16896 B
    int t = threadIdx.x;
    int lane = t & 63, wave = t >> 6;
    int q = blockIdx.x * 4 + wave;
    int s0 = rp[q], s1 = rp[q + 1];
    int cnt = s1 - s0;
    int h = lane >> 4, i = lane & 15;
    const float* lp = logitsT + (size_t)h * NE;

    float m = -INFINITY;
    for (int e = s0 + i; e < s1; e += 16) m = fmaxf(m, lp[e]);
    #pragma unroll
    for (int off = 8; off; off >>= 1) m = fmaxf(m, __shfl_xor(m, off));

    float acc0 = 0.f, acc1 = 0.f, r;

    if (cnt <= 256) {
        int s0a = s0 & ~3;
        float* wpb = wsh + wave * (4 * WCAP) + h * WCAP;
        float sum = 0.f;
        for (int e = s0 + i; e < s1; e += 16) {
            float w = __expf(lp[e] - m);
            wpb[e - s0a] = w;
            sum += w;
        }
        #pragma unroll
        for (int off = 8; off; off >>= 1) sum += __shfl_xor(sum, off);
        r = 1.0f / (sum + 1e-16f);

        int e = s0;
        int e1 = (s0 + 3) & ~3; if (e1 > s1) e1 = s1;
        for (; e < e1; ++e) {
            float w = wpb[e - s0a];
            float2 f = __bfloat1622float2(vb[(size_t)src[e] * 64 + lane]);
            acc0 += w * f.x; acc1 += w * f.y;
        }
        for (; e + 8 <= s1; e += 8) {
            float4 wa = *(const float4*)(wpb + (e - s0a));
            float4 wb = *(const float4*)(wpb + (e - s0a) + 4);
            int4 sa = *(const int4*)(src + e);
            int4 sb = *(const int4*)(src + e + 4);
            float2 f0 = __bfloat1622float2(vb[(size_t)sa.x * 64 + lane]);
            float2 f1 = __bfloat1622float2(vb[(size_t)sa.y * 64 + lane]);
            float2 f2 = __bfloat1622float2(vb[(size_t)sa.z * 64 + lane]);
            float2 f3 = __bfloat1622float2(vb[(size_t)sa.w * 64 + lane]);
            float2 f4 = __bfloat1622float2(vb[(size_t)sb.x * 64 + lane]);
            float2 f5 = __bfloat1622float2(vb[(size_t)sb.y * 64 + lane]);
            float2 f6 = __bfloat1622float2(vb[(size_t)sb.z * 64 + lane]);
            float2 f7 = __bfloat1622float2(vb[(size_t)sb.w * 64 + lane]);
            acc0 += wa.x * f0.x + wa.y * f1.x + wa.z * f2.x + wa.w * f3.x
                  + wb.x * f4.x + wb.y * f5.x + wb.z * f6.x + wb.w * f7.x;
            acc1 += wa.x * f0.y + wa.y * f1.y + wa.z * f2.y + wa.w * f3.y
                  + wb.x * f4.y + wb.y * f5.y + wb.z * f6.y + wb.w * f7.y;
        }
        for (; e + 4 <= s1; e += 4) {
            float4 w4 = *(const float4*)(wpb + (e - s0a));
            int4 s4 = *(const int4*)(src + e);
            float2 f0 = __bfloat1622float2(vb[(size_t)s4.x * 64 + lane]);
            float2 f1 = __bfloat1622float2(vb[(size_t)s4.y * 64 + lane]);
            float2 f2 = __bfloat1622float2(vb[(size_t)s4.z * 64 + lane]);
            float2 f3 = __bfloat1622float2(vb[(size_t)s4.w * 64 + lane]);
            acc0 += w4.x * f0.x + w4.y * f1.x + w4.z * f2.x + w4.w * f3.x;
            acc1 += w4.x * f0.y + w4.y * f1.y + w4.z * f2.y + w4.w * f3.y;
        }
        for (; e < s1; ++e) {
            float w = wpb[e - s0a];
            float2 f = __bfloat1622float2(vb[(size_t)src[e] * 64 + lane]);
            acc0 += w * f.x; acc1 += w * f.y;
        }
    } else {
        float sum = 0.f;
        for (int e = s0 + i; e < s1; e += 16) sum += __expf(lp[e] - m);
        #pragma unroll
        for (int off = 8; off; off >>= 1) sum += __shfl_xor(sum, off);
        r = 1.0f / (sum + 1e-16f);

        int e = s0;
        for (; e < s1 && (e & 3); ++e) {
            float w = __expf(lp[e] - m);
            float2 f = __bfloat1622float2(vb[(size_t)src[e] * 64 + lane]);
            acc0 += w * f.x; acc1 += w * f.y;
        }
        for (; e + 8 <= s1; e += 8) {
            float4 la = *(const float4*)(lp + e);
            float4 lb = *(const float4*)(lp + e + 4);
            int4 sa = *(const int4*)(src + e);
            int4 sb = *(const int4*)(src + e + 4);
            float w0 = __expf(la.x - m), w1 = __expf(la.y - m);
            float w2 = __expf(la.z - m), w3 = __expf(la.w - m);
            float w4 = __expf(lb.x - m), w5 = __expf(lb.y - m);
            float w6 = __expf(lb.z - m), w7 = __expf(lb.w - m);
            float2 f0 = __bfloat1622float2(vb[(size_t)sa.x * 64 + lane]);
            float2 f1 = __bfloat1622float2(vb[(size_t)sa.y * 64 + lane]);
            float2 f2 = __bfloat1622float2(vb[(size_t)sa.z * 64 + lane]);
            float2 f3 = __bfloat1622float2(vb[(size_t)sa.w * 64 + lane]);
            float2 f4 = __bfloat1622float2(vb[(size_t)sb.x * 64 + lane]);
            float2 f5 = __bfloat1622float2(vb[(size_t)sb.y * 64 + lane]);
            float2 f6 = __bfloat1622float2(vb[(size_t)sb.z * 64 + lane]);
            float2 f7 = __bfloat1622float2(vb[(size_t)sb.w * 64 + lane]);
            acc0 += w0 * f0.x + w1 * f1.x + w2 * f2.x + w3 * f3.x
                  + w4 * f4.x + w5 * f5.x + w6 * f6.x + w7 * f7.x;
            acc1 += w0 * f0.y + w1 * f1.y + w2 * f2.y + w3 * f3.y
                  + w4 * f4.y + w5 * f5.y + w6 * f6.y + w7 * f7.y;
        }
        for (; e + 4 <= s1; e += 4) {
            float4 l4 = *(const float4*)(lp + e);
            int4 s4 = *(const int4*)(src + e);
            float w0 = __expf(l4.x - m);
            float w1 = __expf(l4.y - m);
            float w2 = __expf(l4.z - m);
            float w3 = __expf(l4.w - m);
            float2 f0 = __bfloat1622float2(vb[(size_t)s4.x * 64 + lane]);
            float2 f1 = __bfloat1622float2(vb[(size_t)s4.y * 64 + lane]);
            float2 f2 = __bfloat1622float2(vb[(size_t)s4.z * 64 + lane]);
            float2 f3 = __bfloat1622float2(vb[(size_t)s4.w * 64 + lane]);
            acc0 += w0 * f0.x + w1 * f1.x + w2 * f2.x + w3 * f3.x;
            acc1 += w0 * f0.y + w1 * f1.y + w2 * f2.y + w3 * f3.y;
        }
        for (; e < s1; ++e) {
            float w = __expf(lp[e] - m);
            float2 f = __bfloat1622float2(vb[(size_t)src[e] * 64 + lane]);
            acc0 += w * f.x; acc1 += w * f.y;
        }
    }
    *(float2*)(out + (size_t)q * 128 + lane * 2) = make_float2(acc0 * r, acc1 * r);
}

// ---------------------------------------------------------------------------
// ws layout: R0-proven; WvP planes past the high-water mark, runtime-checked.
// ---------------------------------------------------------------------------
extern "C" void kernel_launch(void* const* d_in, const int* in_sizes, int n_in,
                              void* d_out, int out_size, void* d_ws, size_t ws_size,
                              hipStream_t stream) {
    const float* h_obs     = (const float*)d_in[0];
    const float* pos_obs   = (const float*)d_in[1];
    const float* pos_query = (const float*)d_in[2];
    const int*   src       = (const int*)d_in[3];
    const int*   dst       = (const int*)d_in[4];
    const float* W1        = (const float*)d_in[5];
    const float* b1        = (const float*)d_in[6];
    const float* W2        = (const float*)d_in[7];
    const float* b2        = (const float*)d_in[8];
    const float* Wv        = (const float*)d_in[9];
    const float* bv        = (const float*)d_in[10];
    const float* log_sigma = (const float*)d_in[11];
    float* out = (float*)d_out;

    char* ws = (char*)d_ws;
    int*            rp      = (int*)(ws + 0);                   // 50001 ints  (end 200,004)
    float*          scal    = (float*)(ws + 200192);            // 8 floats    (end 200,224)
    unsigned short* W1cT    = (unsigned short*)(ws + 200256);   // 1024 bf16   (end 202,304)
    unsigned short* W2tb    = (unsigned short*)(ws + 202304);   // 512 bf16    (end 203,328)
    unsigned short* vbuf    = (unsigned short*)(ws + 208640);   // 6.4M bf16   (end 13,008,640)
    float*          logitsT = (float*)(ws + 13008768);          // 6.4M floats (end 38,608,768)
    unsigned short* WvPhi   = (unsigned short*)(ws + WVP_OFF);           // 32 KB
    unsigned short* WvPlo   = (unsigned short*)(ws + WVP_OFF + 32768);   // 32 KB

    int vp_mfma = (ws_size >= (size_t)WVP_OFF + WVP_BYTES) ? 1 : 0;

    hipLaunchKernelGGL(pack_kernel, dim3(9), dim3(256), 0, stream,
                       W1, b1, W2, b2, log_sigma, Wv, W1cT, W2tb, scal,
                       WvPhi, WvPlo, vp_mfma);
    hipLaunchKernelGGL(fused_kernel, dim3(EDGE_BLOCKS + VP_BLOCKS + RP_BLOCKS),
                       dim3(128), 0, stream,
                       pos_obs, pos_query, src, dst, W1cT, W2tb, scal, logitsT,
                       h_obs, Wv, bv, vbuf, rp, WvPhi, WvPlo, vp_mfma);
    hipLaunchKernelGGL(attn_kernel, dim3(N_Q / 4), dim3(256), 0, stream,
                       (const __hip_bfloat162*)vbuf, logitsT, src, rp, out);
}